// Round 1
// baseline (1847.958 us; speedup 1.0000x reference)
//
#include <hip/hip_runtime.h>

#define NN 32768
#define NE 1048576

typedef __bf16 bf16_t;
typedef __bf16 bf16x8 __attribute__((ext_vector_type(8)));
typedef float f32x4 __attribute__((ext_vector_type(4)));

// ---------------- absmax(edges_init) -> norm ----------------
__global__ __launch_bounds__(256) void absmax_kernel(const float* __restrict__ x,
                                                     float* __restrict__ norm) {
  int idx = blockIdx.x * 256 + threadIdx.x;          // one float4 per thread, grid covers NE/4
  float4 v = reinterpret_cast<const float4*>(x)[idx];
  float m = fmaxf(fmaxf(fabsf(v.x), fabsf(v.y)), fmaxf(fabsf(v.z), fabsf(v.w)));
#pragma unroll
  for (int off = 32; off > 0; off >>= 1) m = fmaxf(m, __shfl_xor(m, off, 64));
  if ((threadIdx.x & 63) == 0)
    atomicMax(reinterpret_cast<unsigned int*>(norm), __float_as_uint(m)); // vals >= 0: uint order == float order
}

// ---------------- weights -> bf16 B-fragment layout ----------------
// frag layout for v_mfma_f32_16x16x32_bf16 B operand: lane l holds col = nt*16 + (l&15),
// k = kt*32 + (l>>4)*8 + i  (8 contiguous k per lane).
__global__ __launch_bounds__(256) void prep_frags_kernel(const float* __restrict__ W,
                                                         bf16_t* __restrict__ dst, int KT) {
  int idx = blockIdx.x * 256 + threadIdx.x;
  if (idx >= KT * 4 * 64 * 8) return;
  int i = idx & 7, lane = (idx >> 3) & 63, f = idx >> 9;
  int nt = f & 3, kt = f >> 2;
  int k = kt * 32 + ((lane >> 4) << 3) + i;
  int col = nt * 16 + (lane & 15);
  dst[idx] = (bf16_t)W[k * 64 + col];
}

// ---------------- node encoder (fp32, exact) ----------------
__global__ __launch_bounds__(256) void node_encode_kernel(
    const float* __restrict__ nodes, const float* __restrict__ W1, const float* __restrict__ b1,
    const float* __restrict__ W2, const float* __restrict__ b2,
    float* __restrict__ n_f32, bf16_t* __restrict__ n_bf) {
  __shared__ float hs[4][64];
  int wid = threadIdx.x >> 6, k = threadIdx.x & 63;
  int node = blockIdx.x * 4 + wid;
  float x = nodes[node];
  hs[wid][k] = fmaxf(x * W1[k] + b1[k], 0.0f);
  __syncthreads();
  float acc = b2[k];
#pragma unroll 8
  for (int j = 0; j < 64; ++j) acc = fmaf(hs[wid][j], W2[j * 64 + k], acc);
  n_f32[(size_t)node * 64 + k] = acc;
  n_bf[(size_t)node * 64 + k] = (bf16_t)acc;
}

// ---------------- edge encoder: layer1 rank-1 fp32, layer2 bf16 MFMA ----------------
__global__ __launch_bounds__(256) void edge_encode_kernel(
    const float* __restrict__ edges_init, const float* __restrict__ norm_p,
    const float* __restrict__ Wee1, const float* __restrict__ bee1,
    const bf16_t* __restrict__ w2f, const float* __restrict__ bee2,
    bf16_t* __restrict__ e_out) {
  __shared__ alignas(16) bf16_t ht[64][72];
  const int tid = threadIdx.x, lane = tid & 63, wid = tid >> 6;
  const int l15 = lane & 15, lg = lane >> 4;
  const float norm = *norm_p;
  bf16x8 W2[2][4];
#pragma unroll
  for (int kt = 0; kt < 2; ++kt)
#pragma unroll
    for (int nt = 0; nt < 4; ++nt)
      W2[kt][nt] = *reinterpret_cast<const bf16x8*>(w2f + (size_t)((kt * 4 + nt) * 64 + lane) * 8);
  float b2v[4];
#pragma unroll
  for (int nt = 0; nt < 4; ++nt) b2v[nt] = bee2[nt * 16 + l15];

  for (int tile = blockIdx.x; tile < NE / 64; tile += gridDim.x) {
    const int ebase = tile * 64;
    {  // stage h1 tile: 64 edges x 64 hidden, 16 values per thread
      int el = tid >> 2, ksub = (tid & 3) * 16;
      float x = edges_init[ebase + el] / norm;
      bf16x8 h0, h1;
#pragma unroll
      for (int kk = 0; kk < 8; ++kk) {
        h0[kk] = (bf16_t)fmaxf(x * Wee1[ksub + kk] + bee1[ksub + kk], 0.0f);
        h1[kk] = (bf16_t)fmaxf(x * Wee1[ksub + 8 + kk] + bee1[ksub + 8 + kk], 0.0f);
      }
      *reinterpret_cast<bf16x8*>(&ht[el][ksub]) = h0;
      *reinterpret_cast<bf16x8*>(&ht[el][ksub + 8]) = h1;
    }
    __syncthreads();
    const int r0 = wid * 16;
    f32x4 acc[4];
#pragma unroll
    for (int nt = 0; nt < 4; ++nt) acc[nt] = f32x4{b2v[nt], b2v[nt], b2v[nt], b2v[nt]};
#pragma unroll
    for (int kt = 0; kt < 2; ++kt) {
      bf16x8 a = *reinterpret_cast<const bf16x8*>(&ht[r0 + l15][kt * 32 + lg * 8]);
#pragma unroll
      for (int nt = 0; nt < 4; ++nt)
        acc[nt] = __builtin_amdgcn_mfma_f32_16x16x32_bf16(a, W2[kt][nt], acc[nt], 0, 0, 0);
    }
#pragma unroll
    for (int nt = 0; nt < 4; ++nt)
#pragma unroll
      for (int r = 0; r < 4; ++r)
        e_out[(size_t)(ebase + r0 + lg * 4 + r) * 64 + nt * 16 + l15] = (bf16_t)acc[nt][r];
    __syncthreads();
  }
}

// ---------------- CSR build (receivers are static across rounds) ----------------
__global__ __launch_bounds__(256) void count_kernel(const int* __restrict__ recv,
                                                    int* __restrict__ counts) {
  int idx = blockIdx.x * 256 + threadIdx.x;
#pragma unroll
  for (int q = 0; q < 4; ++q) atomicAdd(&counts[recv[q * 262144 + idx]], 1);
}

__global__ __launch_bounds__(1024) void scan_kernel(const int* __restrict__ counts,
                                                    int* __restrict__ row_ptr,
                                                    int* __restrict__ cursor) {
  __shared__ int sums[1024];
  const int t = threadIdx.x;
  int s = 0;
#pragma unroll 4
  for (int i = 0; i < 32; ++i) s += counts[t * 32 + i];
  sums[t] = s;
  __syncthreads();
#pragma unroll
  for (int d = 1; d < 1024; d <<= 1) {
    int v = (t >= d) ? sums[t - d] : 0;
    __syncthreads();
    sums[t] += v;
    __syncthreads();
  }
  int prefix = sums[t] - s;  // exclusive
  for (int i = 0; i < 32; ++i) {
    int idx = t * 32 + i;
    row_ptr[idx] = prefix;
    cursor[idx] = prefix;
    prefix += counts[idx];
  }
  if (t == 1023) row_ptr[NN] = prefix;
}

__global__ __launch_bounds__(256) void scatter_kernel(const int* __restrict__ recv,
                                                      int* __restrict__ cursor,
                                                      int* __restrict__ col_idx) {
  int idx = blockIdx.x * 256 + threadIdx.x;
#pragma unroll
  for (int q = 0; q < 4; ++q) {
    int ei = q * 262144 + idx;
    int pos = atomicAdd(&cursor[recv[ei]], 1);
    col_idx[pos] = ei;
  }
}

// ---------------- edge update: m=[e,n_s,n_r] -> MLP, bf16 MFMA both layers ----------------
__global__ __launch_bounds__(256) void edge_update_kernel(
    const bf16_t* e_in, bf16_t* e_out,  // same buffer: rows disjoint per tile, in-place safe
    const bf16_t* __restrict__ n_bf,
    const int* __restrict__ senders, const int* __restrict__ receivers,
    const bf16_t* __restrict__ w1f, const bf16_t* __restrict__ w2f,
    const float* __restrict__ beu1, const float* __restrict__ beu2) {
  __shared__ alignas(16) bf16_t mt[64][200];  // 64 edges x 192 (pad 200 -> bank-uniform b128)
  __shared__ alignas(16) bf16_t ht[64][72];   // hidden, pad 72
  const int tid = threadIdx.x;
  const int lane = tid & 63, wid = tid >> 6;
  const int l15 = lane & 15, lg = lane >> 4;

  bf16x8 W1[6][4], W2[2][4];  // whole Weu1/Weu2 in VGPRs, loaded once per block
#pragma unroll
  for (int kt = 0; kt < 6; ++kt)
#pragma unroll
    for (int nt = 0; nt < 4; ++nt)
      W1[kt][nt] = *reinterpret_cast<const bf16x8*>(w1f + (size_t)((kt * 4 + nt) * 64 + lane) * 8);
#pragma unroll
  for (int kt = 0; kt < 2; ++kt)
#pragma unroll
    for (int nt = 0; nt < 4; ++nt)
      W2[kt][nt] = *reinterpret_cast<const bf16x8*>(w2f + (size_t)((kt * 4 + nt) * 64 + lane) * 8);
  float b1v[4], b2v[4];
#pragma unroll
  for (int nt = 0; nt < 4; ++nt) {
    b1v[nt] = beu1[nt * 16 + l15];
    b2v[nt] = beu2[nt * 16 + l15];
  }

  for (int tile = blockIdx.x; tile < NE / 64; tile += gridDim.x) {
    const int ebase = tile * 64;
    // stage m = [e | n_s | n_r] as bf16, 16B chunks: 1536 chunks / 256 threads
#pragma unroll
    for (int q = 0; q < 6; ++q) {
      int c = q * 256 + tid;
      int el = c / 24;          // magic-mul div by constant
      int part = c - el * 24;   // 0..23, 8 bf16 each
      int eg = ebase + el;
      const bf16_t* src;
      if (part < 8)       src = e_in + (size_t)eg * 64 + part * 8;
      else if (part < 16) src = n_bf + (size_t)senders[eg] * 64 + (part - 8) * 8;
      else                src = n_bf + (size_t)receivers[eg] * 64 + (part - 16) * 8;
      *reinterpret_cast<bf16x8*>(&mt[el][part * 8]) = *reinterpret_cast<const bf16x8*>(src);
    }
    __syncthreads();
    const int r0 = wid * 16;  // each wave owns 16 edges
    // layer 1: [16,192] @ [192,64]
    f32x4 acc[4];
#pragma unroll
    for (int nt = 0; nt < 4; ++nt) acc[nt] = f32x4{b1v[nt], b1v[nt], b1v[nt], b1v[nt]};
#pragma unroll
    for (int kt = 0; kt < 6; ++kt) {
      bf16x8 a = *reinterpret_cast<const bf16x8*>(&mt[r0 + l15][kt * 32 + lg * 8]);
#pragma unroll
      for (int nt = 0; nt < 4; ++nt)
        acc[nt] = __builtin_amdgcn_mfma_f32_16x16x32_bf16(a, W1[kt][nt], acc[nt], 0, 0, 0);
    }
    // relu -> ht (wave-local rows: no barrier needed, in-wave DS ordering)
#pragma unroll
    for (int nt = 0; nt < 4; ++nt)
#pragma unroll
      for (int r = 0; r < 4; ++r)
        ht[r0 + lg * 4 + r][nt * 16 + l15] = (bf16_t)fmaxf(acc[nt][r], 0.0f);
    // layer 2: [16,64] @ [64,64]
    f32x4 acc2[4];
#pragma unroll
    for (int nt = 0; nt < 4; ++nt) acc2[nt] = f32x4{b2v[nt], b2v[nt], b2v[nt], b2v[nt]};
#pragma unroll
    for (int kt = 0; kt < 2; ++kt) {
      bf16x8 a = *reinterpret_cast<const bf16x8*>(&ht[r0 + l15][kt * 32 + lg * 8]);
#pragma unroll
      for (int nt = 0; nt < 4; ++nt)
        acc2[nt] = __builtin_amdgcn_mfma_f32_16x16x32_bf16(a, W2[kt][nt], acc2[nt], 0, 0, 0);
    }
#pragma unroll
    for (int nt = 0; nt < 4; ++nt)
#pragma unroll
      for (int r = 0; r < 4; ++r)
        e_out[(size_t)(ebase + r0 + lg * 4 + r) * 64 + nt * 16 + l15] = (bf16_t)acc2[nt][r];
    __syncthreads();
  }
}

// ---------------- agg (CSR gather) + node MLP, fp32, one wave per node ----------------
__global__ __launch_bounds__(256) void node_update_kernel(
    const bf16_t* __restrict__ e, const int* __restrict__ row_ptr, const int* __restrict__ col_idx,
    const float* __restrict__ Wnu1, const float* __restrict__ bnu1,
    const float* __restrict__ Wnu2, const float* __restrict__ bnu2,
    float* __restrict__ n_f32, bf16_t* __restrict__ n_bf) {
  __shared__ float xs[4][128];
  __shared__ float hs[4][64];
  const int lane = threadIdx.x & 63, wid = threadIdx.x >> 6;
  for (int tile = blockIdx.x; tile < NN / 4; tile += gridDim.x) {
    const int node = tile * 4 + wid;
    const int p0 = row_ptr[node], p1 = row_ptr[node + 1];
    float agg = 0.0f;
    for (int p = p0; p < p1; ++p) {
      int eidx = col_idx[p];
      agg += (float)e[(size_t)eidx * 64 + lane];  // coalesced 128B row per edge
    }
    xs[wid][lane] = n_f32[(size_t)node * 64 + lane];
    xs[wid][64 + lane] = agg;
    float acc = bnu1[lane];
#pragma unroll 4
    for (int j = 0; j < 128; ++j) acc = fmaf(xs[wid][j], Wnu1[j * 64 + lane], acc);
    hs[wid][lane] = fmaxf(acc, 0.0f);
    float acc2 = bnu2[lane];
#pragma unroll 4
    for (int j = 0; j < 64; ++j) acc2 = fmaf(hs[wid][j], Wnu2[j * 64 + lane], acc2);
    n_f32[(size_t)node * 64 + lane] = acc2;
    n_bf[(size_t)node * 64 + lane] = (bf16_t)acc2;
  }
}

// ---------------- decoder + output mask ----------------
__global__ __launch_bounds__(256) void decode_kernel(
    const bf16_t* __restrict__ e, const bf16_t* __restrict__ wd1f,
    const float* __restrict__ bd1, const float* __restrict__ Wd2, const float* __restrict__ bd2_p,
    const float* __restrict__ edges_init, const int* __restrict__ receivers,
    const int* __restrict__ senders, const float* __restrict__ norm_p,
    const float* __restrict__ alpha_p, float* __restrict__ out) {
  const int tid = threadIdx.x, lane = tid & 63, wid = tid >> 6;
  const int l15 = lane & 15, lg = lane >> 4;
  bf16x8 W1[2][4];
#pragma unroll
  for (int kt = 0; kt < 2; ++kt)
#pragma unroll
    for (int nt = 0; nt < 4; ++nt)
      W1[kt][nt] = *reinterpret_cast<const bf16x8*>(wd1f + (size_t)((kt * 4 + nt) * 64 + lane) * 8);
  float b1v[4], wd2v[4];
#pragma unroll
  for (int nt = 0; nt < 4; ++nt) {
    b1v[nt] = bd1[nt * 16 + l15];
    wd2v[nt] = Wd2[nt * 16 + l15];
  }
  const float norm = *norm_p, alpha = *alpha_p, bd2 = *bd2_p;

  for (int tile = blockIdx.x; tile < NE / 64; tile += gridDim.x) {
    const int ebase = tile * 64;
    const int r0 = wid * 16;
    f32x4 acc[4];
#pragma unroll
    for (int nt = 0; nt < 4; ++nt) acc[nt] = f32x4{b1v[nt], b1v[nt], b1v[nt], b1v[nt]};
#pragma unroll
    for (int kt = 0; kt < 2; ++kt) {
      bf16x8 a = *reinterpret_cast<const bf16x8*>(
          e + (size_t)(ebase + r0 + l15) * 64 + kt * 32 + lg * 8);
#pragma unroll
      for (int nt = 0; nt < 4; ++nt)
        acc[nt] = __builtin_amdgcn_mfma_f32_16x16x32_bf16(a, W1[kt][nt], acc[nt], 0, 0, 0);
    }
    float d[4];
#pragma unroll
    for (int r = 0; r < 4; ++r) {
      float s = 0.0f;
#pragma unroll
      for (int nt = 0; nt < 4; ++nt) s = fmaf(fmaxf(acc[nt][r], 0.0f), wd2v[nt], s);
      s += __shfl_xor(s, 1, 64);
      s += __shfl_xor(s, 2, 64);
      s += __shfl_xor(s, 4, 64);
      s += __shfl_xor(s, 8, 64);
      d[r] = s + bd2;
    }
    if (l15 == 0) {
      int erow = ebase + r0 + lg * 4;
#pragma unroll
      for (int r = 0; r < 4; ++r) {
        int eg = erow + r;
        out[eg] = (receivers[eg] >= senders[eg]) ? (edges_init[eg] + alpha * (d[r] * norm)) : 0.0f;
      }
    }
  }
}

extern "C" void kernel_launch(void* const* d_in, const int* in_sizes, int n_in,
                              void* d_out, int out_size, void* d_ws, size_t ws_size,
                              hipStream_t stream) {
  const float* nodes      = (const float*)d_in[0];
  const float* edges_init = (const float*)d_in[1];
  const int*   receivers  = (const int*)d_in[2];
  const int*   senders    = (const int*)d_in[3];
  const float* Wne1 = (const float*)d_in[4];
  const float* bne1 = (const float*)d_in[5];
  const float* Wne2 = (const float*)d_in[6];
  const float* bne2 = (const float*)d_in[7];
  const float* Wee1 = (const float*)d_in[8];
  const float* bee1 = (const float*)d_in[9];
  const float* Wee2 = (const float*)d_in[10];
  const float* bee2 = (const float*)d_in[11];
  const float* Weu1 = (const float*)d_in[12];
  const float* beu1 = (const float*)d_in[13];
  const float* Weu2 = (const float*)d_in[14];
  const float* beu2 = (const float*)d_in[15];
  const float* Wnu1 = (const float*)d_in[16];
  const float* bnu1 = (const float*)d_in[17];
  const float* Wnu2 = (const float*)d_in[18];
  const float* bnu2 = (const float*)d_in[19];
  const float* Wd1  = (const float*)d_in[20];
  const float* bd1  = (const float*)d_in[21];
  const float* Wd2  = (const float*)d_in[22];
  const float* bd2  = (const float*)d_in[23];
  const float* alpha = (const float*)d_in[24];
  float* out = (float*)d_out;
  (void)in_sizes; (void)n_in; (void)out_size; (void)ws_size;

  char* ws = (char*)d_ws;
  size_t off = 0;
  auto alloc = [&](size_t bytes) -> void* {
    void* p = ws + off;
    off = (off + bytes + 255) & ~(size_t)255;
    return p;
  };
  float*  norm    = (float*)alloc(4);
  int*    counts  = (int*)alloc(sizeof(int) * NN);
  int*    row_ptr = (int*)alloc(sizeof(int) * (NN + 1));
  int*    cursor  = (int*)alloc(sizeof(int) * (NN + 1));
  int*    col_idx = (int*)alloc(sizeof(int) * NE);
  float*  n_f32   = (float*)alloc(sizeof(float) * (size_t)NN * 64);
  bf16_t* n_bf    = (bf16_t*)alloc(sizeof(bf16_t) * (size_t)NN * 64);
  bf16_t* e_buf   = (bf16_t*)alloc(sizeof(bf16_t) * (size_t)NE * 64);
  bf16_t* w1f     = (bf16_t*)alloc(sizeof(bf16_t) * 6 * 4 * 64 * 8);
  bf16_t* w2f     = (bf16_t*)alloc(sizeof(bf16_t) * 2 * 4 * 64 * 8);
  bf16_t* wee2f   = (bf16_t*)alloc(sizeof(bf16_t) * 2 * 4 * 64 * 8);
  bf16_t* wd1f    = (bf16_t*)alloc(sizeof(bf16_t) * 2 * 4 * 64 * 8);

  hipMemsetAsync(norm, 0, 4, stream);
  hipMemsetAsync(counts, 0, sizeof(int) * NN, stream);

  absmax_kernel<<<NE / 1024, 256, 0, stream>>>(edges_init, norm);
  prep_frags_kernel<<<48, 256, 0, stream>>>(Weu1, w1f, 6);
  prep_frags_kernel<<<16, 256, 0, stream>>>(Weu2, w2f, 2);
  prep_frags_kernel<<<16, 256, 0, stream>>>(Wee2, wee2f, 2);
  prep_frags_kernel<<<16, 256, 0, stream>>>(Wd1, wd1f, 2);

  node_encode_kernel<<<NN / 4, 256, 0, stream>>>(nodes, Wne1, bne1, Wne2, bne2, n_f32, n_bf);
  edge_encode_kernel<<<4096, 256, 0, stream>>>(edges_init, norm, Wee1, bee1, wee2f, bee2, e_buf);

  count_kernel<<<1024, 256, 0, stream>>>(receivers, counts);
  scan_kernel<<<1, 1024, 0, stream>>>(counts, row_ptr, cursor);
  scatter_kernel<<<1024, 256, 0, stream>>>(receivers, cursor, col_idx);

  for (int t = 0; t < 5; ++t) {
    edge_update_kernel<<<4096, 256, 0, stream>>>(e_buf, e_buf, n_bf, senders, receivers,
                                                 w1f, w2f, beu1, beu2);
    if (t < 4)  // last round's node state is never consumed
      node_update_kernel<<<2048, 256, 0, stream>>>(e_buf, row_ptr, col_idx,
                                                   Wnu1, bnu1, Wnu2, bnu2, n_f32, n_bf);
  }
  decode_kernel<<<4096, 256, 0, stream>>>(e_buf, wd1f, bd1, Wd2, bd2, edges_init,
                                          receivers, senders, norm, alpha, out);
}

// Round 2
// 1127.992 us; speedup vs baseline: 1.6383x; 1.6383x over previous
//
#include <hip/hip_runtime.h>

#define NN 32768
#define NE 1048576

typedef __bf16 bf16_t;
typedef __bf16 bf16x8 __attribute__((ext_vector_type(8)));
typedef __bf16 bf16x4 __attribute__((ext_vector_type(4)));
typedef float f32x4 __attribute__((ext_vector_type(4)));

// ---------------- absmax(edges_init) -> norm ----------------
__global__ __launch_bounds__(256) void absmax_kernel(const float* __restrict__ x,
                                                     float* __restrict__ norm) {
  int idx = blockIdx.x * 256 + threadIdx.x;
  float4 v = reinterpret_cast<const float4*>(x)[idx];
  float m = fmaxf(fmaxf(fabsf(v.x), fabsf(v.y)), fmaxf(fabsf(v.z), fabsf(v.w)));
#pragma unroll
  for (int off = 32; off > 0; off >>= 1) m = fmaxf(m, __shfl_xor(m, off, 64));
  if ((threadIdx.x & 63) == 0)
    atomicMax(reinterpret_cast<unsigned int*>(norm), __float_as_uint(m));
}

// ---------------- weights -> bf16 fragment layout ----------------
// Fragment (A or B) for v_mfma_f32_16x16x32_bf16: lane l holds dim (l&15),
// k = (l>>4)*8 + i. Stored frag-major: frag f=(kt*4+nt), then lane, then i.
__global__ __launch_bounds__(256) void prep_frags_kernel(const float* __restrict__ W,
                                                         bf16_t* __restrict__ dst, int KT) {
  int idx = blockIdx.x * 256 + threadIdx.x;
  if (idx >= KT * 4 * 64 * 8) return;
  int i = idx & 7, lane = (idx >> 3) & 63, f = idx >> 9;
  int nt = f & 3, kt = f >> 2;
  int k = kt * 32 + ((lane >> 4) << 3) + i;
  int col = nt * 16 + (lane & 15);
  dst[idx] = (bf16_t)W[k * 64 + col];
}

// ---------------- node encoder (fp32, exact) ----------------
__global__ __launch_bounds__(256) void node_encode_kernel(
    const float* __restrict__ nodes, const float* __restrict__ W1, const float* __restrict__ b1,
    const float* __restrict__ W2, const float* __restrict__ b2,
    float* __restrict__ n_f32, bf16_t* __restrict__ n_bf) {
  __shared__ float hs[4][64];
  int wid = threadIdx.x >> 6, k = threadIdx.x & 63;
  int node = blockIdx.x * 4 + wid;
  float x = nodes[node];
  hs[wid][k] = fmaxf(x * W1[k] + b1[k], 0.0f);
  __syncthreads();
  float acc = b2[k];
#pragma unroll 8
  for (int j = 0; j < 64; ++j) acc = fmaf(hs[wid][j], W2[j * 64 + k], acc);
  n_f32[(size_t)node * 64 + k] = acc;
  n_bf[(size_t)node * 64 + k] = (bf16_t)acc;
}

// ---------------- CSR build ----------------
__global__ __launch_bounds__(256) void count_kernel(const int* __restrict__ recv,
                                                    int* __restrict__ counts) {
  int idx = blockIdx.x * 256 + threadIdx.x;
#pragma unroll
  for (int q = 0; q < 4; ++q) atomicAdd(&counts[recv[q * 262144 + idx]], 1);
}

__global__ __launch_bounds__(1024) void scan_kernel(const int* __restrict__ counts,
                                                    int* __restrict__ row_ptr,
                                                    int* __restrict__ cursor) {
  __shared__ int sums[1024];
  const int t = threadIdx.x;
  int s = 0;
#pragma unroll 4
  for (int i = 0; i < 32; ++i) s += counts[t * 32 + i];
  sums[t] = s;
  __syncthreads();
#pragma unroll
  for (int d = 1; d < 1024; d <<= 1) {
    int v = (t >= d) ? sums[t - d] : 0;
    __syncthreads();
    sums[t] += v;
    __syncthreads();
  }
  int prefix = sums[t] - s;  // exclusive
  for (int i = 0; i < 32; ++i) {
    int idx = t * 32 + i;
    row_ptr[idx] = prefix;
    cursor[idx] = prefix;
    prefix += counts[idx];
  }
  if (t == 1023) row_ptr[NN] = prefix;
}

__global__ __launch_bounds__(256) void scatter_kernel(const int* __restrict__ recv,
                                                      int* __restrict__ cursor,
                                                      int* __restrict__ col_idx) {
  int idx = blockIdx.x * 256 + threadIdx.x;
#pragma unroll
  for (int q = 0; q < 4; ++q) {
    int ei = q * 262144 + idx;
    int pos = atomicAdd(&cursor[recv[ei]], 1);
    col_idx[pos] = ei;  // permutation: CSR position p -> original edge id
  }
}

// ---------------- edge encoder: wave-independent, no staging ----------------
__global__ __launch_bounds__(256) void edge_encode_kernel(
    const float* __restrict__ edges_init, const int* __restrict__ col_idx,
    const float* __restrict__ norm_p,
    const float* __restrict__ Wee1, const float* __restrict__ bee1,
    const bf16_t* __restrict__ w2f, const float* __restrict__ bee2,
    bf16_t* __restrict__ e_out) {
  const int lane = threadIdx.x & 63, wid = threadIdx.x >> 6;
  const int l15 = lane & 15, lg = lane >> 4;
  const float invn = 1.0f / *norm_p;
  bf16x8 W2[2][4];
#pragma unroll
  for (int kt = 0; kt < 2; ++kt)
#pragma unroll
    for (int nt = 0; nt < 4; ++nt)
      W2[kt][nt] = *reinterpret_cast<const bf16x8*>(w2f + (size_t)((kt * 4 + nt) * 64 + lane) * 8);
  float4 b2q[4];
#pragma unroll
  for (int nt = 0; nt < 4; ++nt) b2q[nt] = *reinterpret_cast<const float4*>(bee2 + nt * 16 + lg * 4);
  float4 wa0 = *reinterpret_cast<const float4*>(Wee1 + lg * 8);
  float4 wa1 = *reinterpret_cast<const float4*>(Wee1 + lg * 8 + 4);
  float4 wb0 = *reinterpret_cast<const float4*>(Wee1 + 32 + lg * 8);
  float4 wb1 = *reinterpret_cast<const float4*>(Wee1 + 32 + lg * 8 + 4);
  float4 ba0 = *reinterpret_cast<const float4*>(bee1 + lg * 8);
  float4 ba1 = *reinterpret_cast<const float4*>(bee1 + lg * 8 + 4);
  float4 bb0 = *reinterpret_cast<const float4*>(bee1 + 32 + lg * 8);
  float4 bb1 = *reinterpret_cast<const float4*>(bee1 + 32 + lg * 8 + 4);

  const int NW = gridDim.x * 4, NGRP = NE / 16;
  for (int g = blockIdx.x * 4 + wid; g < NGRP; g += NW) {
    int row = g * 16 + l15;
    float x = edges_init[col_idx[row]] * invn;
    bf16x8 h0, h1;
#pragma unroll
    for (int i = 0; i < 4; ++i) {
      h0[i]     = (bf16_t)fmaxf(x * ((const float*)&wa0)[i] + ((const float*)&ba0)[i], 0.0f);
      h0[i + 4] = (bf16_t)fmaxf(x * ((const float*)&wa1)[i] + ((const float*)&ba1)[i], 0.0f);
      h1[i]     = (bf16_t)fmaxf(x * ((const float*)&wb0)[i] + ((const float*)&bb0)[i], 0.0f);
      h1[i + 4] = (bf16_t)fmaxf(x * ((const float*)&wb1)[i] + ((const float*)&bb1)[i], 0.0f);
    }
    f32x4 acc[4];
#pragma unroll
    for (int nt = 0; nt < 4; ++nt)
      acc[nt] = f32x4{b2q[nt].x, b2q[nt].y, b2q[nt].z, b2q[nt].w};
#pragma unroll
    for (int nt = 0; nt < 4; ++nt) {
      acc[nt] = __builtin_amdgcn_mfma_f32_16x16x32_bf16(W2[0][nt], h0, acc[nt], 0, 0, 0);
      acc[nt] = __builtin_amdgcn_mfma_f32_16x16x32_bf16(W2[1][nt], h1, acc[nt], 0, 0, 0);
    }
    // D^T: lane holds e[row=g*16+l15][hid=nt*16+lg*4+r]
#pragma unroll
    for (int nt = 0; nt < 4; ++nt) {
      bf16x4 pk;
#pragma unroll
      for (int r = 0; r < 4; ++r) pk[r] = (bf16_t)acc[nt][r];
      *reinterpret_cast<bf16x4*>(e_out + (size_t)row * 64 + nt * 16 + lg * 4) = pk;
    }
  }
}

// ---------------- edge update: wave-independent, swapped MFMA, W in LDS ----------------
__global__ __launch_bounds__(256) void edge_update_kernel(
    bf16_t* __restrict__ e,  // permuted layout, in/out (rows owned per wave)
    const bf16_t* __restrict__ n_bf, const int* __restrict__ col_idx,
    const int* __restrict__ senders, const int* __restrict__ receivers,
    const bf16_t* __restrict__ wglob,  // 24 frags W1 + 8 frags W2
    const float* __restrict__ beu1, const float* __restrict__ beu2) {
  __shared__ alignas(16) bf16_t wlds[16384];     // 32 KB
  __shared__ alignas(16) bf16_t tr[4][16][72];   // per-wave h transpose
  const int tid = threadIdx.x, lane = tid & 63, wid = tid >> 6;
  const int l15 = lane & 15, lg = lane >> 4;
#pragma unroll
  for (int j = 0; j < 8; ++j)
    reinterpret_cast<bf16x8*>(wlds)[j * 256 + tid] =
        reinterpret_cast<const bf16x8*>(wglob)[j * 256 + tid];
  __syncthreads();  // only barrier in the kernel

  float4 b1q[4], b2q[4];
#pragma unroll
  for (int nt = 0; nt < 4; ++nt) {
    b1q[nt] = *reinterpret_cast<const float4*>(beu1 + nt * 16 + lg * 4);
    b2q[nt] = *reinterpret_cast<const float4*>(beu2 + nt * 16 + lg * 4);
  }

  const int NW = gridDim.x * 4, NGRP = NE / 16;
  const int g0 = blockIdx.x * 4 + wid;
  // software pipeline: prefetch indices + own e-row one group ahead
  int si, ri;
  bf16x8 pe0, pe1;
  {
    int row = g0 * 16 + l15;
    int o = col_idx[row];
    si = senders[o];
    ri = receivers[o];
    const bf16x8* er = reinterpret_cast<const bf16x8*>(e + (size_t)row * 64);
    pe0 = er[lg];
    pe1 = er[4 + lg];
  }
  for (int g = g0; g < NGRP; g += NW) {
    const bf16x8* sr = reinterpret_cast<const bf16x8*>(n_bf + (size_t)si * 64);
    bf16x8 as0 = sr[lg], as1 = sr[4 + lg];
    const bf16x8* rr = reinterpret_cast<const bf16x8*>(n_bf + (size_t)ri * 64);
    bf16x8 ar0 = rr[lg], ar1 = rr[4 + lg];
    bf16x8 ae0 = pe0, ae1 = pe1;
    int gn = g + NW;
    if (gn < NGRP) {
      int row = gn * 16 + l15;
      int o = col_idx[row];
      si = senders[o];
      ri = receivers[o];
      const bf16x8* er = reinterpret_cast<const bf16x8*>(e + (size_t)row * 64);
      pe0 = er[lg];
      pe1 = er[4 + lg];
    }
    // layer 1 (swapped): D^T[h][edge] = W1^T . m^T ; B operand = m rows direct
    f32x4 acc[4];
#pragma unroll
    for (int nt = 0; nt < 4; ++nt)
      acc[nt] = f32x4{b1q[nt].x, b1q[nt].y, b1q[nt].z, b1q[nt].w};
    const bf16x8 am[6] = {ae0, ae1, as0, as1, ar0, ar1};
#pragma unroll
    for (int kt = 0; kt < 6; ++kt) {
#pragma unroll
      for (int nt = 0; nt < 4; ++nt) {
        bf16x8 w = *reinterpret_cast<const bf16x8*>(wlds + ((kt * 4 + nt) * 64 + lane) * 8);
        acc[nt] = __builtin_amdgcn_mfma_f32_16x16x32_bf16(w, am[kt], acc[nt], 0, 0, 0);
      }
    }
    // relu -> per-wave LDS transpose (lane holds h[hid=nt*16+lg*4+r][edge=l15])
#pragma unroll
    for (int nt = 0; nt < 4; ++nt) {
      bf16x4 pk;
#pragma unroll
      for (int r = 0; r < 4; ++r) pk[r] = (bf16_t)fmaxf(acc[nt][r], 0.0f);
      *reinterpret_cast<bf16x4*>(&tr[wid][l15][nt * 16 + lg * 4]) = pk;
    }
    bf16x8 h0 = *reinterpret_cast<const bf16x8*>(&tr[wid][l15][lg * 8]);
    bf16x8 h1 = *reinterpret_cast<const bf16x8*>(&tr[wid][l15][32 + lg * 8]);
    // layer 2 (swapped)
    f32x4 acc2[4];
#pragma unroll
    for (int nt = 0; nt < 4; ++nt)
      acc2[nt] = f32x4{b2q[nt].x, b2q[nt].y, b2q[nt].z, b2q[nt].w};
#pragma unroll
    for (int nt = 0; nt < 4; ++nt) {
      bf16x8 w0 = *reinterpret_cast<const bf16x8*>(wlds + ((24 + nt) * 64 + lane) * 8);
      bf16x8 w1 = *reinterpret_cast<const bf16x8*>(wlds + ((28 + nt) * 64 + lane) * 8);
      acc2[nt] = __builtin_amdgcn_mfma_f32_16x16x32_bf16(w0, h0, acc2[nt], 0, 0, 0);
      acc2[nt] = __builtin_amdgcn_mfma_f32_16x16x32_bf16(w1, h1, acc2[nt], 0, 0, 0);
    }
    // store directly: lane holds e_new[edge=l15][hid=nt*16+lg*4+r]
#pragma unroll
    for (int nt = 0; nt < 4; ++nt) {
      bf16x4 pk;
#pragma unroll
      for (int r = 0; r < 4; ++r) pk[r] = (bf16_t)acc2[nt][r];
      *reinterpret_cast<bf16x4*>(e + (size_t)(g * 16 + l15) * 64 + nt * 16 + lg * 4) = pk;
    }
  }
}

// ---------------- node update: sequential CSR segment + fp32 MLP ----------------
__global__ __launch_bounds__(256) void node_update_kernel(
    const bf16_t* __restrict__ e, const int* __restrict__ row_ptr,
    const float* __restrict__ Wnu1, const float* __restrict__ bnu1,
    const float* __restrict__ Wnu2, const float* __restrict__ bnu2,
    float* __restrict__ n_f32, bf16_t* __restrict__ n_bf) {
  __shared__ float xs[4][128];
  __shared__ float hs[4][64];
  const int lane = threadIdx.x & 63, wid = threadIdx.x >> 6;
  for (int tile = blockIdx.x; tile < NN / 4; tile += gridDim.x) {
    const int node = tile * 4 + wid;
    const int p0 = row_ptr[node], cnt = row_ptr[node + 1] - p0;
    const bf16_t* bp = e + (size_t)p0 * 64 + lane;
    float a0 = 0, a1 = 0, a2 = 0, a3 = 0;
    int p = 0;
    for (; p + 4 <= cnt; p += 4) {  // contiguous rows: fully coalesced, 4 in flight
      a0 += (float)bp[(size_t)(p + 0) * 64];
      a1 += (float)bp[(size_t)(p + 1) * 64];
      a2 += (float)bp[(size_t)(p + 2) * 64];
      a3 += (float)bp[(size_t)(p + 3) * 64];
    }
    for (; p < cnt; ++p) a0 += (float)bp[(size_t)p * 64];
    float agg = (a0 + a1) + (a2 + a3);
    xs[wid][lane] = n_f32[(size_t)node * 64 + lane];
    xs[wid][64 + lane] = agg;
    float acc = bnu1[lane];
#pragma unroll 4
    for (int j = 0; j < 128; ++j) acc = fmaf(xs[wid][j], Wnu1[j * 64 + lane], acc);
    hs[wid][lane] = fmaxf(acc, 0.0f);
    float acc2 = bnu2[lane];
#pragma unroll 4
    for (int j = 0; j < 64; ++j) acc2 = fmaf(hs[wid][j], Wnu2[j * 64 + lane], acc2);
    n_f32[(size_t)node * 64 + lane] = acc2;
    n_bf[(size_t)node * 64 + lane] = (bf16_t)acc2;
  }
}

// ---------------- decoder + mask + scatter back to original order ----------------
__global__ __launch_bounds__(256) void decode_kernel(
    const bf16_t* __restrict__ e, const bf16_t* __restrict__ wd1f,
    const float* __restrict__ bd1, const float* __restrict__ Wd2, const float* __restrict__ bd2_p,
    const float* __restrict__ edges_init, const int* __restrict__ col_idx,
    const int* __restrict__ receivers, const int* __restrict__ senders,
    const float* __restrict__ norm_p, const float* __restrict__ alpha_p,
    float* __restrict__ out) {
  const int lane = threadIdx.x & 63, wid = threadIdx.x >> 6;
  const int l15 = lane & 15, lg = lane >> 4;
  bf16x8 W1[2][4];
#pragma unroll
  for (int kt = 0; kt < 2; ++kt)
#pragma unroll
    for (int nt = 0; nt < 4; ++nt)
      W1[kt][nt] = *reinterpret_cast<const bf16x8*>(wd1f + (size_t)((kt * 4 + nt) * 64 + lane) * 8);
  float4 b1q[4], w2q[4];
#pragma unroll
  for (int nt = 0; nt < 4; ++nt) {
    b1q[nt] = *reinterpret_cast<const float4*>(bd1 + nt * 16 + lg * 4);
    w2q[nt] = *reinterpret_cast<const float4*>(Wd2 + nt * 16 + lg * 4);
  }
  const float norm = *norm_p, alpha = *alpha_p, bd2 = *bd2_p;

  const int NW = gridDim.x * 4, NGRP = NE / 16;
  for (int g = blockIdx.x * 4 + wid; g < NGRP; g += NW) {
    int row = g * 16 + l15;
    const bf16x8* er = reinterpret_cast<const bf16x8*>(e + (size_t)row * 64);
    bf16x8 e0 = er[lg], e1 = er[4 + lg];
    f32x4 acc[4];
#pragma unroll
    for (int nt = 0; nt < 4; ++nt)
      acc[nt] = f32x4{b1q[nt].x, b1q[nt].y, b1q[nt].z, b1q[nt].w};
#pragma unroll
    for (int nt = 0; nt < 4; ++nt) {
      acc[nt] = __builtin_amdgcn_mfma_f32_16x16x32_bf16(W1[0][nt], e0, acc[nt], 0, 0, 0);
      acc[nt] = __builtin_amdgcn_mfma_f32_16x16x32_bf16(W1[1][nt], e1, acc[nt], 0, 0, 0);
    }
    float s = 0.0f;
#pragma unroll
    for (int nt = 0; nt < 4; ++nt)
#pragma unroll
      for (int r = 0; r < 4; ++r)
        s = fmaf(fmaxf(acc[nt][r], 0.0f), ((const float*)&w2q[nt])[r], s);
    s += __shfl_xor(s, 16, 64);
    s += __shfl_xor(s, 32, 64);  // lanes with same l15 now hold full dot product
    if (lg == 0) {
      int o = col_idx[row];
      out[o] = (receivers[o] >= senders[o])
                   ? (edges_init[o] + alpha * ((s + bd2) * norm))
                   : 0.0f;
    }
  }
}

extern "C" void kernel_launch(void* const* d_in, const int* in_sizes, int n_in,
                              void* d_out, int out_size, void* d_ws, size_t ws_size,
                              hipStream_t stream) {
  const float* nodes      = (const float*)d_in[0];
  const float* edges_init = (const float*)d_in[1];
  const int*   receivers  = (const int*)d_in[2];
  const int*   senders    = (const int*)d_in[3];
  const float* Wne1 = (const float*)d_in[4];
  const float* bne1 = (const float*)d_in[5];
  const float* Wne2 = (const float*)d_in[6];
  const float* bne2 = (const float*)d_in[7];
  const float* Wee1 = (const float*)d_in[8];
  const float* bee1 = (const float*)d_in[9];
  const float* Wee2 = (const float*)d_in[10];
  const float* bee2 = (const float*)d_in[11];
  const float* Weu1 = (const float*)d_in[12];
  const float* beu1 = (const float*)d_in[13];
  const float* Weu2 = (const float*)d_in[14];
  const float* beu2 = (const float*)d_in[15];
  const float* Wnu1 = (const float*)d_in[16];
  const float* bnu1 = (const float*)d_in[17];
  const float* Wnu2 = (const float*)d_in[18];
  const float* bnu2 = (const float*)d_in[19];
  const float* Wd1  = (const float*)d_in[20];
  const float* bd1  = (const float*)d_in[21];
  const float* Wd2  = (const float*)d_in[22];
  const float* bd2  = (const float*)d_in[23];
  const float* alpha = (const float*)d_in[24];
  float* out = (float*)d_out;
  (void)in_sizes; (void)n_in; (void)out_size; (void)ws_size;

  char* ws = (char*)d_ws;
  size_t off = 0;
  auto alloc = [&](size_t bytes) -> void* {
    void* p = ws + off;
    off = (off + bytes + 255) & ~(size_t)255;
    return p;
  };
  float*  norm    = (float*)alloc(4);
  int*    counts  = (int*)alloc(sizeof(int) * NN);
  int*    row_ptr = (int*)alloc(sizeof(int) * (NN + 1));
  int*    cursor  = (int*)alloc(sizeof(int) * (NN + 1));
  int*    col_idx = (int*)alloc(sizeof(int) * NE);
  float*  n_f32   = (float*)alloc(sizeof(float) * (size_t)NN * 64);
  bf16_t* n_bf    = (bf16_t*)alloc(sizeof(bf16_t) * (size_t)NN * 64);
  bf16_t* e_buf   = (bf16_t*)alloc(sizeof(bf16_t) * (size_t)NE * 64);  // permuted order
  bf16_t* weu     = (bf16_t*)alloc(sizeof(bf16_t) * (6 + 2) * 4 * 64 * 8);
  bf16_t* wee2f   = (bf16_t*)alloc(sizeof(bf16_t) * 2 * 4 * 64 * 8);
  bf16_t* wd1f    = (bf16_t*)alloc(sizeof(bf16_t) * 2 * 4 * 64 * 8);

  hipMemsetAsync(norm, 0, 4, stream);
  hipMemsetAsync(counts, 0, sizeof(int) * NN, stream);

  absmax_kernel<<<NE / 1024, 256, 0, stream>>>(edges_init, norm);
  prep_frags_kernel<<<48, 256, 0, stream>>>(Weu1, weu, 6);
  prep_frags_kernel<<<16, 256, 0, stream>>>(Weu2, weu + 6 * 4 * 64 * 8, 2);
  prep_frags_kernel<<<16, 256, 0, stream>>>(Wee2, wee2f, 2);
  prep_frags_kernel<<<16, 256, 0, stream>>>(Wd1, wd1f, 2);

  node_encode_kernel<<<NN / 4, 256, 0, stream>>>(nodes, Wne1, bne1, Wne2, bne2, n_f32, n_bf);

  count_kernel<<<1024, 256, 0, stream>>>(receivers, counts);
  scan_kernel<<<1, 1024, 0, stream>>>(counts, row_ptr, cursor);
  scatter_kernel<<<1024, 256, 0, stream>>>(receivers, cursor, col_idx);

  edge_encode_kernel<<<8192, 256, 0, stream>>>(edges_init, col_idx, norm,
                                               Wee1, bee1, wee2f, bee2, e_buf);

  for (int t = 0; t < 5; ++t) {
    edge_update_kernel<<<4096, 256, 0, stream>>>(e_buf, n_bf, col_idx, senders, receivers,
                                                 weu, beu1, beu2);
    if (t < 4)
      node_update_kernel<<<2048, 256, 0, stream>>>(e_buf, row_ptr,
                                                   Wnu1, bnu1, Wnu2, bnu2, n_f32, n_bf);
  }
  decode_kernel<<<8192, 256, 0, stream>>>(e_buf, wd1f, bd1, Wd2, bd2, edges_init, col_idx,
                                          receivers, senders, norm, alpha, out);
}